// Round 1
// baseline (2362.991 us; speedup 1.0000x reference)
//
#include <hip/hip_runtime.h>

#define N_PTS 32768
#define K_CB  8192
#define D_DIM 256

// ws layout (element offsets in floats unless noted)
#define CB_OFF   0                       // codebook: K_CB*D_DIM floats (2,097,152)
#define CC_OFF   (K_CB * D_DIM)          // ||c||^2: K_CB floats
#define ZZ_OFF   (CC_OFF + K_CB)         // ||z||^2: N_PTS floats
#define IDX_OFF  (ZZ_OFF + N_PTS)        // indices: N_PTS ints
#define ACC_BYTE ((size_t)(IDX_OFF + N_PTS) * 4)  // double accumulator (8B aligned)

// ---------------------------------------------------------------------------
// Kernel 1: codebook[k][d] = sum_j emb[k][j]*W[d][j] + b[d];  cc[k] = ||c_k||^2
// Sequential-j fma chain to mimic a canonical fp32 GEMM accumulation order.
// ---------------------------------------------------------------------------
__global__ __launch_bounds__(256) void k_codebook(
    const float* __restrict__ emb, const float* __restrict__ w,
    const float* __restrict__ b, float* __restrict__ cb, float* __restrict__ cc) {
  __shared__ float es[D_DIM];
  __shared__ float row[D_DIM];
  const int k = blockIdx.x;
  const int d = threadIdx.x;
  es[d] = emb[k * D_DIM + d];
  __syncthreads();
  const float* wr = w + d * D_DIM;
  float a = 0.f;
#pragma unroll 8
  for (int q = 0; q < D_DIM / 4; ++q) {
    float4 wv = *(const float4*)&wr[q * 4];
    a = fmaf(es[q * 4 + 0], wv.x, a);
    a = fmaf(es[q * 4 + 1], wv.y, a);
    a = fmaf(es[q * 4 + 2], wv.z, a);
    a = fmaf(es[q * 4 + 3], wv.w, a);
  }
  a += b[d];
  cb[k * D_DIM + d] = a;
  row[d] = a;
  __syncthreads();
  // redundant sequential sum of squares (all lanes, LDS broadcast -> no conflict)
  float s = 0.f;
#pragma unroll 8
  for (int j = 0; j < D_DIM; ++j) s = fmaf(row[j], row[j], s);
  if (d == 0) cc[k] = s;
}

// ---------------------------------------------------------------------------
// Kernel 2: zz[n] = ||z_n||^2, sequential order per row.
// ---------------------------------------------------------------------------
__global__ __launch_bounds__(256) void k_zz(const float* __restrict__ z,
                                            float* __restrict__ zz) {
  const int n = blockIdx.x * 256 + threadIdx.x;
  const float* zr = z + (size_t)n * D_DIM;
  float s = 0.f;
#pragma unroll 8
  for (int q = 0; q < D_DIM / 4; ++q) {
    float4 v = *(const float4*)&zr[q * 4];
    s = fmaf(v.x, v.x, s);
    s = fmaf(v.y, v.y, s);
    s = fmaf(v.z, v.z, s);
    s = fmaf(v.w, v.w, s);
  }
  zz[n] = s;
}

// ---------------------------------------------------------------------------
// Kernel 3: distances + argmin.
// Grid 512 blocks; block tile = 64 z-rows x 8192 codes (looped in 128-code
// tiles), depth chunks of 32 in LDS. Thread micro-tile: 4 rows x 8 codes.
// d(n,k) = (zz[n] + cc[k]) - 2*dot  (fma -> single rounding, matches a-b form)
// tie-break: first (lowest) k, matching jnp.argmin.
// ---------------------------------------------------------------------------
#define BN  64
#define BKC 128
#define DC  32
#define LDP (DC + 4)  // stride 36 floats: 16B-aligned rows, benign bank aliasing

__global__ __launch_bounds__(256) void k_argmin(
    const float* __restrict__ z, const float* __restrict__ cb,
    const float* __restrict__ zz, const float* __restrict__ cc,
    int* __restrict__ out_idx) {
  __shared__ float zs[BN][LDP];
  __shared__ float cs[BKC][LDP];
  __shared__ float red_d[BN][16];
  __shared__ int   red_k[BN][16];

  const int tid = threadIdx.x;
  const int tn = tid & 15;   // row group (16)
  const int tk = tid >> 4;   // col group (16)
  const int n0 = blockIdx.x * BN;

  float zzv[4];
#pragma unroll
  for (int i = 0; i < 4; ++i) zzv[i] = zz[n0 + tn + 16 * i];

  float best[4];
  int   bidx[4];
#pragma unroll
  for (int i = 0; i < 4; ++i) { best[i] = 3.4e38f; bidx[i] = 0; }

  for (int kt = 0; kt < K_CB / BKC; ++kt) {
    float acc[4][8];
#pragma unroll
    for (int i = 0; i < 4; ++i)
#pragma unroll
      for (int j = 0; j < 8; ++j) acc[i][j] = 0.f;

    for (int ch = 0; ch < D_DIM / DC; ++ch) {
      __syncthreads();
      // stage z chunk: 64x32 floats = 512 float4
#pragma unroll
      for (int s = 0; s < 2; ++s) {
        int f = tid + 256 * s;
        int r = f >> 3, c4 = f & 7;
        *(float4*)&zs[r][c4 * 4] =
            *(const float4*)&z[(size_t)(n0 + r) * D_DIM + ch * DC + c4 * 4];
      }
      // stage c chunk: 128x32 floats = 1024 float4
#pragma unroll
      for (int s = 0; s < 4; ++s) {
        int f = tid + 256 * s;
        int r = f >> 3, c4 = f & 7;
        *(float4*)&cs[r][c4 * 4] =
            *(const float4*)&cb[(size_t)(kt * BKC + r) * D_DIM + ch * DC + c4 * 4];
      }
      __syncthreads();

#pragma unroll
      for (int q = 0; q < DC / 4; ++q) {
        float4 zr[4], cr[8];
#pragma unroll
        for (int i = 0; i < 4; ++i) zr[i] = *(const float4*)&zs[tn + 16 * i][4 * q];
#pragma unroll
        for (int j = 0; j < 8; ++j) cr[j] = *(const float4*)&cs[tk + 16 * j][4 * q];
#pragma unroll
        for (int i = 0; i < 4; ++i)
#pragma unroll
          for (int j = 0; j < 8; ++j) {
            acc[i][j] = fmaf(zr[i].x, cr[j].x, acc[i][j]);
            acc[i][j] = fmaf(zr[i].y, cr[j].y, acc[i][j]);
            acc[i][j] = fmaf(zr[i].z, cr[j].z, acc[i][j]);
            acc[i][j] = fmaf(zr[i].w, cr[j].w, acc[i][j]);
          }
      }
    }
    // fold this code tile into the running argmin (k ascending within thread)
#pragma unroll
    for (int j = 0; j < 8; ++j) {
      const int k = kt * BKC + tk + 16 * j;
      const float cck = cc[k];
#pragma unroll
      for (int i = 0; i < 4; ++i) {
        float t = zzv[i] + cck;
        float dd = fmaf(-2.f, acc[i][j], t);
        if (dd < best[i]) { best[i] = dd; bidx[i] = k; }
      }
    }
  }

  // cross-thread reduce: 16 threads (tk) share each local row tn+16i
#pragma unroll
  for (int i = 0; i < 4; ++i) {
    red_d[tn + 16 * i][tk] = best[i];
    red_k[tn + 16 * i][tk] = bidx[i];
  }
  __syncthreads();
  if (tid < BN) {
    float bd = red_d[tid][0];
    int   bk = red_k[tid][0];
#pragma unroll
    for (int t2 = 1; t2 < 16; ++t2) {
      float dd = red_d[tid][t2];
      int   kk = red_k[tid][t2];
      if (dd < bd || (dd == bd && kk < bk)) { bd = dd; bk = kk; }
    }
    out_idx[n0 + tid] = bk;
  }
}

// ---------------------------------------------------------------------------
// Kernel 4: zq gather + straight-through output + loss partial sums.
// One wave handles one row at a time (64 lanes x float4 = 256 floats).
// ---------------------------------------------------------------------------
__global__ __launch_bounds__(256) void k_gather(
    const float* __restrict__ z, const float* __restrict__ cb,
    const int* __restrict__ idx, float* __restrict__ out,
    double* __restrict__ accum) {
  const int tid = threadIdx.x;
  const int lane = tid & 63, wv = tid >> 6;
  const int base = blockIdx.x * 64 + wv * 16;
  double lsum = 0.0;
  for (int r = 0; r < 16; ++r) {
    const int n = base + r;
    const int k = idx[n];
    float4 c4 = *(const float4*)&cb[(size_t)k * D_DIM + lane * 4];
    float4 z4 = *(const float4*)&z[(size_t)n * D_DIM + lane * 4];
    float e0 = c4.x - z4.x, e1 = c4.y - z4.y, e2 = c4.z - z4.z, e3 = c4.w - z4.w;
    lsum += (double)e0 * e0 + (double)e1 * e1 + (double)e2 * e2 + (double)e3 * e3;
    float4 o;
    o.x = z4.x + e0; o.y = z4.y + e1; o.z = z4.z + e2; o.w = z4.w + e3;
    *(float4*)&out[(size_t)n * D_DIM + lane * 4] = o;
    if (lane == 0) out[(size_t)N_PTS * D_DIM + n] = (float)k;
  }
  // block reduction of lsum
#pragma unroll
  for (int off = 32; off > 0; off >>= 1) lsum += __shfl_down(lsum, off);
  __shared__ double wsum[4];
  if (lane == 0) wsum[wv] = lsum;
  __syncthreads();
  if (tid == 0) atomicAdd(accum, wsum[0] + wsum[1] + wsum[2] + wsum[3]);
}

// ---------------------------------------------------------------------------
// Kernel 5: loss = 0.5*m + m, m = mean((zq-z)^2)
// ---------------------------------------------------------------------------
__global__ void k_loss(const double* __restrict__ accum, float* __restrict__ out) {
  float m = (float)(*accum / (double)((size_t)N_PTS * D_DIM));
  out[(size_t)N_PTS * D_DIM + N_PTS] = 0.5f * m + m;
}

extern "C" void kernel_launch(void* const* d_in, const int* in_sizes, int n_in,
                              void* d_out, int out_size, void* d_ws, size_t ws_size,
                              hipStream_t stream) {
  const float* z   = (const float*)d_in[0];
  const float* emb = (const float*)d_in[1];
  const float* w   = (const float*)d_in[2];
  const float* b   = (const float*)d_in[3];
  float* out = (float*)d_out;

  float*  ws_f  = (float*)d_ws;
  float*  cb    = ws_f + CB_OFF;
  float*  cc    = ws_f + CC_OFF;
  float*  zz    = ws_f + ZZ_OFF;
  int*    idx   = (int*)(ws_f + IDX_OFF);
  double* accum = (double*)((char*)d_ws + ACC_BYTE);

  hipMemsetAsync(accum, 0, sizeof(double), stream);

  k_codebook<<<K_CB, 256, 0, stream>>>(emb, w, b, cb, cc);
  k_zz<<<N_PTS / 256, 256, 0, stream>>>(z, zz);
  k_argmin<<<N_PTS / BN, 256, 0, stream>>>(z, cb, zz, cc, idx);
  k_gather<<<N_PTS / 64, 256, 0, stream>>>(z, cb, idx, out, accum);
  k_loss<<<1, 1, 0, stream>>>(accum, out);
}